// Round 1
// baseline (2070.686 us; speedup 1.0000x reference)
//
#include <hip/hip_runtime.h>

#define BATCH 4
#define T 8192
#define RES 256
#define SKIPC 512
#define NCLSC 256
#define NLAYERS 30
#define T0 5120
#define TBUF 3072
#define NT 32
#define STR 264               // LDS row stride in shorts (528 B): 2-way banks, 16B-aligned
#define TAPSZ (NT * STR)      // 8448 shorts per tap buffer
#define GRIDP 256             // persistent grid: 1 block/CU guaranteed co-resident

typedef __attribute__((ext_vector_type(8))) short short8x;   // 8 bf16
typedef __attribute__((ext_vector_type(4))) float floatx4;   // MFMA C/D
typedef unsigned short ushort_t;
typedef unsigned long long ull;

__device__ __forceinline__ ushort_t f2bf(float f) {
    unsigned u = __float_as_uint(f);
    u += 0x7fffu + ((u >> 16) & 1u);
    return (ushort_t)(u >> 16);
}
__device__ __forceinline__ float bf2f(ushort_t h) {
    return __uint_as_float(((unsigned)h) << 16);
}

// Weight prep: Aswz/Rswz are stored in exact MFMA A-fragment load order so the
// kernel's A-loads are base + lane*16B (fully coalesced).
// Aswz[l][wv(8)][s(16)][f(2)][lane(64)][j(8)]; row=wv*32+f*16+(lane&15), k=s*32+(lane>>4)*8+j
// Rswz[l][wv(8)][s(8)][f(2)][lane(64)][j(8)];  same, k<256
// WsT[l][cin][o]
__global__ __launch_bounds__(256) void prep_kernel(
    const float* __restrict__ Wd, const float* __restrict__ Wr,
    const float* __restrict__ Ws,
    ushort_t* __restrict__ Aswz, ushort_t* __restrict__ Rswz,
    ushort_t* __restrict__ WsT)
{
    long id = (long)blockIdx.x * 256 + threadIdx.x;
    const long R0 = 30L * 131072, R1 = 30L * 65536, R2 = 30L * 131072;
    if (id < R0) {
        long l = id >> 17; int r = (int)(id & 131071);
        int j = r & 7, lane = (r >> 3) & 63, f = (r >> 9) & 1, s = (r >> 10) & 15, wv = r >> 14;
        int row = wv * 32 + f * 16 + (lane & 15);
        int k = s * 32 + (lane >> 4) * 8 + j;
        int cin = k & 255, kk = k >> 8;
        Aswz[id] = f2bf(Wd[((l * 256 + row) * 256 + cin) * 2 + kk]);
        return;
    }
    id -= R0;
    if (id < R1) {
        long l = id >> 16; int r = (int)(id & 65535);
        int j = r & 7, lane = (r >> 3) & 63, f = (r >> 9) & 1, s = (r >> 10) & 7, wv = r >> 13;
        int row = wv * 32 + f * 16 + (lane & 15);
        int k = s * 32 + (lane >> 4) * 8 + j;
        Rswz[id] = f2bf(Wr[(l * 256 + row) * 256 + k]);
        return;
    }
    id -= R1;
    if (id < R2) {
        int o = (int)(id & 511); long rest = id >> 9; int cin = (int)(rest & 255); long l = rest >> 8;
        WsT[id] = f2bf(Ws[(l * 512 + o) * 256 + cin]);
    }
}

// h0[b][t][c] for t in [5120, 8191], fp32 + bf16 copies.
__global__ __launch_bounds__(256) void start_kernel(
    const float* __restrict__ x, const float* __restrict__ Wst,
    const float* __restrict__ bst, float* __restrict__ hf, ushort_t* __restrict__ hb)
{
    int id = blockIdx.x * 256 + threadIdx.x;
    int c = id & 255;
    int ti = (id >> 8) % TBUF;
    int b  = (id >> 8) / TBUF;
    int t = T0 + ti;
    float v = Wst[2 * c] * x[b * T + t - 1] + Wst[2 * c + 1] * x[b * T + t] + bst[c];
    hf[id] = v;
    hb[id] = f2bf(v);
}

// Sense-reversing grid barrier. bar[0]=count, bar[32]=generation (separate lines).
// Deadlock-free: grid=GRIDP=256 blocks, each 8 waves / 33.8KB LDS / <=256 VGPR
// (__launch_bounds__(512)) -> at least 1 block/CU schedulable -> all co-resident.
// __syncthreads drains each wave's vmcnt; thread-0's agent-scope fence then
// publishes the whole block's stores across XCD L2s (release/acquire pairing).
__device__ __forceinline__ void grid_barrier(int* bar) {
    __syncthreads();
    if (threadIdx.x == 0) {
        __threadfence();                                   // release (agent)
        int g = __hip_atomic_load(bar + 32, __ATOMIC_RELAXED, __HIP_MEMORY_SCOPE_AGENT);
        int v = __hip_atomic_fetch_add(bar, 1, __ATOMIC_ACQ_REL, __HIP_MEMORY_SCOPE_AGENT);
        if (v == GRIDP - 1) {
            __hip_atomic_store(bar, 0, __ATOMIC_RELAXED, __HIP_MEMORY_SCOPE_AGENT);
            __hip_atomic_store(bar + 32, g + 1, __ATOMIC_RELEASE, __HIP_MEMORY_SCOPE_AGENT);
        } else {
            while (__hip_atomic_load(bar + 32, __ATOMIC_ACQUIRE, __HIP_MEMORY_SCOPE_AGENT) == g)
                __builtin_amdgcn_s_sleep(2);
        }
        __threadfence();                                   // acquire (agent)
    }
    __syncthreads();
}

// All 30 WaveNet layers in ONE persistent kernel: in-kernel layer loop with a
// device-scope grid barrier between layers. Removes 30 serialized launch+drain
// round-trips. Inner (tile,b) unit body is identical to the verified
// layer_kernel. 512 thr = 8 waves, tile 256(M) x 32(N).
__global__ __launch_bounds__(512) void fused_layers_kernel(
    float* __restrict__ hf,
    ushort_t* __restrict__ hb0, ushort_t* __restrict__ hb1,
    const ushort_t* __restrict__ Asw,
    const float* __restrict__ bd,
    const ushort_t* __restrict__ Rsw,
    const float* __restrict__ br,
    float* __restrict__ gstore,
    int* __restrict__ bar)
{
    __shared__ __align__(16) ushort_t st[2 * TAPSZ];   // 33.8 KB; gated overlays tap0

    const int tid = threadIdx.x;
    const int wv = tid >> 6, lane = tid & 63;
    const int quad = lane >> 4, l16 = lane & 15;
    const int mb = wv * 32;
    const int u0 = l16 * STR + quad * 8;
    const int u1 = u0 + 16 * STR;

    int rem = 3069;                                    // rem[0] = sum of all dilations
    for (int i = 0; i < NLAYERS; ++i) {
        const int dil = 1 << (i % 10);
        rem -= dil;                                    // rem[i+1]
        const int s_out = 8191 - rem;
        const int ntiles = (8192 - s_out + NT - 1) / NT;
        const int nunits = ntiles * BATCH;

        const ushort_t* __restrict__ hbA = (i & 1) ? hb1 : hb0;
        ushort_t* __restrict__ hbB = (i & 1) ? hb0 : hb1;
        const ushort_t* __restrict__ aw =
            Asw + (size_t)i * (RES * 512) + (size_t)wv * 16384 + lane * 8;
        const ushort_t* __restrict__ rw =
            Rsw + (size_t)i * (RES * RES) + (size_t)wv * 8192 + lane * 8;
        const float* __restrict__ bdL = bd + i * RES;
        const float* __restrict__ brL = br + i * RES;
        float* __restrict__ gsL = gstore + (size_t)i * (BATCH * RES);

        for (int u = blockIdx.x; u < nunits; u += GRIDP) {
            const int tile = u % ntiles;
            const int b = u / ntiles;
            const int tb = 8192 - NT * (tile + 1);

            float* __restrict__ hfb = hf + (size_t)b * TBUF * RES;
            const ushort_t* __restrict__ hA = hbA + (size_t)b * TBUF * RES;
            ushort_t* __restrict__ hB = hbB + (size_t)b * TBUF * RES;

            __syncthreads();   // previous unit's LDS readers done before restaging

            // Stage tap0 (t-dil) and tap1 (t): 32 rows x 512 B each, coalesced 16 B.
            #pragma unroll
            for (int tp = 0; tp < 2; ++tp) {
                const int dsub = tp ? 0 : dil;
                #pragma unroll
                for (int p = 0; p < 2; ++p) {
                    int c = p * 512 + tid;
                    int row = c >> 5, off = (c & 31) * 8;
                    int tt = tb + row - dsub - T0;
                    tt = tt < 0 ? 0 : tt;            // junk cols discarded in epilogue
                    *(float4*)&st[tp * TAPSZ + row * STR + off] =
                        *(const float4*)(hA + (size_t)tt * RES + off);
                }
            }
            __syncthreads();

            floatx4 acc00, acc01, acc10, acc11;
            {
                float4 c0 = *(const float4*)(bdL + mb + quad * 4);
                float4 c1 = *(const float4*)(bdL + mb + 16 + quad * 4);
                acc00 = acc01 = (floatx4){c0.x, c0.y, c0.z, c0.w};
                acc10 = acc11 = (floatx4){c1.x, c1.y, c1.z, c1.w};
            }

            // Conv GEMM: K=512 (s<8: tap0 = t-dil, s>=8: tap1 = t)
            #pragma unroll
            for (int s = 0; s < 16; ++s) {
                const int tbs = (s < 8 ? 0 : TAPSZ) + (s & 7) * 32;
                short8x a0 = *(const short8x*)(aw + s * 1024);
                short8x a1 = *(const short8x*)(aw + s * 1024 + 512);
                short8x g0 = *(const short8x*)&st[tbs + u0];
                short8x g1 = *(const short8x*)&st[tbs + u1];
                acc00 = __builtin_amdgcn_mfma_f32_16x16x32_bf16(a0, g0, acc00, 0, 0, 0);
                acc10 = __builtin_amdgcn_mfma_f32_16x16x32_bf16(a1, g0, acc10, 0, 0, 0);
                acc01 = __builtin_amdgcn_mfma_f32_16x16x32_bf16(a0, g1, acc01, 0, 0, 0);
                acc11 = __builtin_amdgcn_mfma_f32_16x16x32_bf16(a1, g1, acc11, 0, 0, 0);
            }
            __syncthreads();   // conv LDS reads done before gated overlays tap0

            // gate -> LDS gl[n][cin] (overlay tap0); capture t=8191 col fp32
            #pragma unroll
            for (int mt = 0; mt < 2; ++mt) {
                #pragma unroll
                for (int nt = 0; nt < 2; ++nt) {
                    floatx4 a = mt == 0 ? (nt == 0 ? acc00 : acc01) : (nt == 0 ? acc10 : acc11);
                    float gf[4];
                    ull pk = 0;
                    #pragma unroll
                    for (int r = 0; r < 4; ++r) {
                        float d = a[r];
                        float sig = 1.f / (1.f + __expf(-d));
                        float th = 1.f - 2.f / (__expf(2.f * d) + 1.f);
                        gf[r] = th * sig;
                        pk |= ((ull)f2bf(gf[r])) << (16 * r);
                    }
                    const int n = nt * 16 + l16;
                    const int m = mb + mt * 16 + quad * 4;
                    *(ull*)&st[n * STR + m] = pk;
                    if (tile == 0 && n == 31) {
                        float4 g4 = {gf[0], gf[1], gf[2], gf[3]};
                        *(float4*)&gsL[b * RES + m] = g4;
                    }
                }
            }
            __syncthreads();

            // Residual GEMM: h' = h + Wr @ gated, K=256
            floatx4 r00, r01, r10, r11;
            {
                float4 c0 = *(const float4*)(brL + mb + quad * 4);
                float4 c1 = *(const float4*)(brL + mb + 16 + quad * 4);
                r00 = r01 = (floatx4){c0.x, c0.y, c0.z, c0.w};
                r10 = r11 = (floatx4){c1.x, c1.y, c1.z, c1.w};
            }
            #pragma unroll
            for (int s = 0; s < 8; ++s) {
                short8x a0 = *(const short8x*)(rw + s * 1024);
                short8x a1 = *(const short8x*)(rw + s * 1024 + 512);
                short8x g0 = *(const short8x*)&st[s * 32 + u0];
                short8x g1 = *(const short8x*)&st[s * 32 + u1];
                r00 = __builtin_amdgcn_mfma_f32_16x16x32_bf16(a0, g0, r00, 0, 0, 0);
                r10 = __builtin_amdgcn_mfma_f32_16x16x32_bf16(a1, g0, r10, 0, 0, 0);
                r01 = __builtin_amdgcn_mfma_f32_16x16x32_bf16(a0, g1, r01, 0, 0, 0);
                r11 = __builtin_amdgcn_mfma_f32_16x16x32_bf16(a1, g1, r11, 0, 0, 0);
            }

            // Epilogue: in-place fp32 residual add + bf16 copy; only valid columns
            #pragma unroll
            for (int nt = 0; nt < 2; ++nt) {
                const int t = tb + nt * 16 + l16;
                if (t < s_out) continue;
                const size_t base = (size_t)(t - T0) * RES;
                #pragma unroll
                for (int mt = 0; mt < 2; ++mt) {
                    const int m = mb + mt * 16 + quad * 4;
                    floatx4 ad = mt == 0 ? (nt == 0 ? r00 : r01) : (nt == 0 ? r10 : r11);
                    float4 ho = *(const float4*)(hfb + base + m);
                    float4 hn = {ho.x + ad[0], ho.y + ad[1], ho.z + ad[2], ho.w + ad[3]};
                    *(float4*)(hfb + base + m) = hn;
                    ull pk = (ull)f2bf(hn.x) | ((ull)f2bf(hn.y) << 16)
                           | ((ull)f2bf(hn.z) << 32) | ((ull)f2bf(hn.w) << 48);
                    *(ull*)(hB + base + m) = pk;
                }
            }
        }

        if (i != NLAYERS - 1) grid_barrier(bar);
    }
}

// All 30 skip matvecs in parallel: block (l,b), thread o
__global__ __launch_bounds__(512) void skip_kernel(
    const ushort_t* __restrict__ WsT, const float* __restrict__ bs,
    const float* __restrict__ gstore, float* __restrict__ skip)
{
    const int l = blockIdx.x, b = blockIdx.y, o = threadIdx.x;
    const ushort_t* w = WsT + (size_t)l * 131072;
    const float* g = gstore + (size_t)(l * BATCH + b) * RES;
    float a = bs[l * SKIPC + o];
    #pragma unroll 4
    for (int cin = 0; cin < RES; ++cin)
        a = fmaf(bf2f(w[cin * SKIPC + o]), g[cin], a);
    atomicAdd(&skip[b * SKIPC + o], a);
}

// e1[b][o] = relu(W1 @ relu(skip[b]) + b1); grid (B, 16), block computes 32 outputs
__global__ __launch_bounds__(256) void end1_kernel(
    const float* __restrict__ skip, const float* __restrict__ W1,
    const float* __restrict__ b1, float* __restrict__ e1ws)
{
    __shared__ float s[SKIPC];
    __shared__ float part[256];
    const int b = blockIdx.x, og = blockIdx.y, tid = threadIdx.x;
    s[tid]       = fmaxf(skip[b * SKIPC + tid], 0.f);
    s[tid + 256] = fmaxf(skip[b * SKIPC + tid + 256], 0.f);
    __syncthreads();
    const int o_l = tid >> 3, kp = tid & 7;
    const int o = og * 32 + o_l;
    const float* w = W1 + (size_t)o * SKIPC + kp * 64;
    const float* sp = s + kp * 64;
    float a = 0.f;
    #pragma unroll 8
    for (int j = 0; j < 64; ++j) a = fmaf(w[j], sp[j], a);
    part[tid] = a;
    __syncthreads();
    if (tid < 32) {
        float r = b1[og * 32 + tid];
        #pragma unroll
        for (int k = 0; k < 8; ++k) r += part[tid * 8 + k];
        e1ws[b * SKIPC + og * 32 + tid] = fmaxf(r, 0.f);
    }
}

// out[b][cls] = W2 @ e1 + b2; grid (B, 8), block computes 32 outputs
__global__ __launch_bounds__(256) void end2_kernel(
    const float* __restrict__ e1ws, const float* __restrict__ W2,
    const float* __restrict__ b2, float* __restrict__ out)
{
    __shared__ float e[SKIPC];
    __shared__ float part[256];
    const int b = blockIdx.x, og = blockIdx.y, tid = threadIdx.x;
    e[tid]       = e1ws[b * SKIPC + tid];
    e[tid + 256] = e1ws[b * SKIPC + tid + 256];
    __syncthreads();
    const int o_l = tid >> 3, kp = tid & 7;
    const int cls = og * 32 + o_l;
    const float* w = W2 + (size_t)cls * SKIPC + kp * 64;
    const float* ep = e + kp * 64;
    float a = 0.f;
    #pragma unroll 8
    for (int j = 0; j < 64; ++j) a = fmaf(w[j], ep[j], a);
    part[tid] = a;
    __syncthreads();
    if (tid < 32) {
        float r = b2[og * 32 + tid];
        #pragma unroll
        for (int k = 0; k < 8; ++k) r += part[tid * 8 + k];
        out[b * NCLSC + og * 32 + tid] = r;
    }
}

extern "C" void kernel_launch(void* const* d_in, const int* in_sizes, int n_in,
                              void* d_out, int out_size, void* d_ws, size_t ws_size,
                              hipStream_t stream)
{
    const float* x   = (const float*)d_in[0];
    const float* Wst = (const float*)d_in[1];
    const float* bst = (const float*)d_in[2];
    const float* Wd  = (const float*)d_in[3];
    const float* bd  = (const float*)d_in[4];
    const float* Wr  = (const float*)d_in[5];
    const float* br  = (const float*)d_in[6];
    const float* Ws  = (const float*)d_in[7];
    const float* bs  = (const float*)d_in[8];
    const float* W1  = (const float*)d_in[9];
    const float* b1  = (const float*)d_in[10];
    const float* W2  = (const float*)d_in[11];
    const float* b2  = (const float*)d_in[12];
    float* out = (float*)d_out;

    char* w = (char*)d_ws;
    float* hf     = (float*)w;     w += (size_t)BATCH * TBUF * RES * 4;
    ushort_t* hb0 = (ushort_t*)w;  w += (size_t)BATCH * TBUF * RES * 2;
    ushort_t* hb1 = (ushort_t*)w;  w += (size_t)BATCH * TBUF * RES * 2;
    ushort_t* Asw = (ushort_t*)w;  w += (size_t)NLAYERS * RES * 512 * 2;
    ushort_t* Rsw = (ushort_t*)w;  w += (size_t)NLAYERS * RES * RES * 2;
    ushort_t* WsT = (ushort_t*)w;  w += (size_t)NLAYERS * RES * SKIPC * 2;
    float* gstore = (float*)w;     w += (size_t)NLAYERS * BATCH * RES * 4;
    float* skip   = (float*)w;     w += (size_t)BATCH * SKIPC * 4;
    float* e1ws   = (float*)w;     w += (size_t)BATCH * SKIPC * 4;
    int* bar      = (int*)w;       w += 256;

    prep_kernel<<<38400, 256, 0, stream>>>(Wd, Wr, Ws, Asw, Rsw, WsT);
    start_kernel<<<(BATCH * TBUF * RES) / 256, 256, 0, stream>>>(x, Wst, bst, hf, hb0);
    hipMemsetAsync(skip, 0, BATCH * SKIPC * 4, stream);
    hipMemsetAsync(bar, 0, 256, stream);

    fused_layers_kernel<<<GRIDP, 512, 0, stream>>>(
        hf, hb0, hb1, Asw, bd, Rsw, br, gstore, bar);

    skip_kernel<<<dim3(NLAYERS, BATCH), 512, 0, stream>>>(WsT, bs, gstore, skip);
    end1_kernel<<<dim3(BATCH, 16), 256, 0, stream>>>(skip, W1, b1, e1ws);
    end2_kernel<<<dim3(BATCH, 8), 256, 0, stream>>>(e1ws, W2, b2, out);
}

// Round 2
// 728.194 us; speedup vs baseline: 2.8436x; 2.8436x over previous
//
#include <hip/hip_runtime.h>

#define BATCH 4
#define T 8192
#define RES 256
#define SKIPC 512
#define NCLSC 256
#define NLAYERS 30
#define T0 5120
#define TBUF 3072
#define NT 32
#define STR 264               // LDS row stride in shorts (528 B): 2-way banks, 16B-aligned
#define TAPSZ (NT * STR)      // 8448 shorts per tap buffer
#define GRIDP 384             // = max units/layer; 2 blocks/CU guaranteed -> all co-resident
#define MAXTILES 96

typedef __attribute__((ext_vector_type(8))) short short8x;   // 8 bf16
typedef __attribute__((ext_vector_type(4))) float floatx4;   // MFMA C/D
typedef unsigned short ushort_t;
typedef unsigned long long ull;

__device__ __forceinline__ ushort_t f2bf(float f) {
    unsigned u = __float_as_uint(f);
    u += 0x7fffu + ((u >> 16) & 1u);
    return (ushort_t)(u >> 16);
}
__device__ __forceinline__ float bf2f(ushort_t h) {
    return __uint_as_float(((unsigned)h) << 16);
}

// Coherent (cross-XCD) 8B access helpers: relaxed agent-scope atomics lower to
// sc1 loads/stores (bypass/write-through L2) with NO cache-maintenance insts,
// so the normal L2 path (weights!) stays hot.
__device__ __forceinline__ ull cload(const ull* p) {
    return __hip_atomic_load(p, __ATOMIC_RELAXED, __HIP_MEMORY_SCOPE_AGENT);
}
__device__ __forceinline__ void cstore(ull* p, ull v) {
    __hip_atomic_store(p, v, __ATOMIC_RELAXED, __HIP_MEMORY_SCOPE_AGENT);
}

// Weight prep: Aswz/Rswz are stored in exact MFMA A-fragment load order so the
// kernel's A-loads are base + lane*16B (fully coalesced).
__global__ __launch_bounds__(256) void prep_kernel(
    const float* __restrict__ Wd, const float* __restrict__ Wr,
    const float* __restrict__ Ws,
    ushort_t* __restrict__ Aswz, ushort_t* __restrict__ Rswz,
    ushort_t* __restrict__ WsT)
{
    long id = (long)blockIdx.x * 256 + threadIdx.x;
    const long R0 = 30L * 131072, R1 = 30L * 65536, R2 = 30L * 131072;
    if (id < R0) {
        long l = id >> 17; int r = (int)(id & 131071);
        int j = r & 7, lane = (r >> 3) & 63, f = (r >> 9) & 1, s = (r >> 10) & 15, wv = r >> 14;
        int row = wv * 32 + f * 16 + (lane & 15);
        int k = s * 32 + (lane >> 4) * 8 + j;
        int cin = k & 255, kk = k >> 8;
        Aswz[id] = f2bf(Wd[((l * 256 + row) * 256 + cin) * 2 + kk]);
        return;
    }
    id -= R0;
    if (id < R1) {
        long l = id >> 16; int r = (int)(id & 65535);
        int j = r & 7, lane = (r >> 3) & 63, f = (r >> 9) & 1, s = (r >> 10) & 7, wv = r >> 13;
        int row = wv * 32 + f * 16 + (lane & 15);
        int k = s * 32 + (lane >> 4) * 8 + j;
        Rswz[id] = f2bf(Wr[(l * 256 + row) * 256 + k]);
        return;
    }
    id -= R1;
    if (id < R2) {
        int o = (int)(id & 511); long rest = id >> 9; int cin = (int)(rest & 255); long l = rest >> 8;
        WsT[id] = f2bf(Ws[(l * 512 + o) * 256 + cin]);
    }
}

// h0[b][t][c] for t in [5120, 8191], fp32 + bf16 copies.
__global__ __launch_bounds__(256) void start_kernel(
    const float* __restrict__ x, const float* __restrict__ Wst,
    const float* __restrict__ bst, float* __restrict__ hf, ushort_t* __restrict__ hb)
{
    int id = blockIdx.x * 256 + threadIdx.x;
    int c = id & 255;
    int ti = (id >> 8) % TBUF;
    int b  = (id >> 8) / TBUF;
    int t = T0 + ti;
    float v = Wst[2 * c] * x[b * T + t - 1] + Wst[2 * c + 1] * x[b * T + t] + bst[c];
    hf[id] = v;
    hb[id] = f2bf(v);
}

#define WAITF(P) while (__hip_atomic_load((P), __ATOMIC_RELAXED, __HIP_MEMORY_SCOPE_AGENT) == 0) \
                     __builtin_amdgcn_s_sleep(1)

// All 30 layers, dataflow-pipelined: per-(layer,batch,tile) ready flags replace
// any global barrier (no L2-flushing fences -> weights stay L2-hot). Activation
// traffic (hf/hb) uses agent-coherent 8B atomics. Block B owns unit B (<= 1 unit
// per layer since GRIDP = max nunits); layers shrink monotonically so idle
// blocks exit. __launch_bounds__(512,4) caps VGPR at 128 -> 2 blocks/CU -> all
// 384 blocks co-resident -> flag waits are deadlock-free.
__global__ __launch_bounds__(512, 4) void fused_layers_kernel(
    float* __restrict__ hf,
    ushort_t* __restrict__ hb0, ushort_t* __restrict__ hb1,
    const ushort_t* __restrict__ Asw,
    const float* __restrict__ bd,
    const ushort_t* __restrict__ Rsw,
    const float* __restrict__ br,
    float* __restrict__ gstore,
    int* __restrict__ flg)
{
    __shared__ __align__(16) ushort_t st[2 * TAPSZ];   // 33.8 KB; gated overlays tap0

    const int tid = threadIdx.x;
    const int wv = tid >> 6, lane = tid & 63;
    const int quad = lane >> 4, l16 = lane & 15;
    const int mb = wv * 32;
    const int u0 = l16 * STR + quad * 8;
    const int u1 = u0 + 16 * STR;
    const int B = blockIdx.x;

    int rem = 3069;
    int ntiles_prev = 0;
    for (int i = 0; i < NLAYERS; ++i) {
        const int dil = 1 << (i % 10);
        rem -= dil;                                    // rem[i+1]
        const int s_out = 8191 - rem;
        const int ntiles = (8192 - s_out + NT - 1) >> 5;
        if (B >= ntiles * BATCH) break;                // shrinking grids: done forever

        const int tile = B % ntiles;
        const int b = B / ntiles;
        const int tb = 8192 - NT * (tile + 1);

        const ushort_t* __restrict__ hbA = (i & 1) ? hb1 : hb0;
        ushort_t* __restrict__ hbB = (i & 1) ? hb0 : hb1;
        const ushort_t* __restrict__ aw =
            Asw + (size_t)i * (RES * 512) + (size_t)wv * 16384 + lane * 8;
        const ushort_t* __restrict__ rw =
            Rsw + (size_t)i * (RES * RES) + (size_t)wv * 8192 + lane * 8;
        const float* __restrict__ bdL = bd + i * RES;
        const float* __restrict__ brL = br + i * RES;

        float* __restrict__ hfb = hf + (size_t)b * TBUF * RES;
        const ushort_t* __restrict__ hA = hbA + (size_t)b * TBUF * RES;
        ushort_t* __restrict__ hB = hbB + (size_t)b * TBUF * RES;

        // Wait for the <=3 producer tiles of the previous layer this tile reads:
        // own columns [tb, tb+31] (tap1 + hf RMW) and [tb-dil, tb+31-dil] (tap0).
        if (i > 0 && tid == 0) {
            int* fp = flg + ((i - 1) * BATCH + b) * MAXTILES;
            int ta  = (NT * tile + dil) >> 5;
            int tbb = (NT * tile + NT - 1 + dil) >> 5;
            if (tbb > ntiles_prev - 1) tbb = ntiles_prev - 1;   // stale region: junk cols, discarded
            if (ta > tbb) ta = tbb;
            WAITF(fp + tile);
            WAITF(fp + ta);
            if (tbb != ta) WAITF(fp + tbb);
        }
        __syncthreads();   // flag observed by all; also: prev layer's LDS reads done

        // Stage tap0 (t-dil) and tap1 (t): coherent 8B loads (written cross-XCD).
        #pragma unroll
        for (int tp = 0; tp < 2; ++tp) {
            const int dsub = tp ? 0 : dil;
            #pragma unroll
            for (int p = 0; p < 2; ++p) {
                int c = p * 512 + tid;
                int row = c >> 5, off = (c & 31) * 8;
                int tt = tb + row - dsub - T0;
                tt = tt < 0 ? 0 : tt;            // junk cols discarded in epilogue
                const ull* src = (const ull*)(hA + (size_t)tt * RES + off);
                ull v0 = cload(src);
                ull v1 = cload(src + 1);
                ull* dst = (ull*)&st[tp * TAPSZ + row * STR + off];
                dst[0] = v0;
                dst[1] = v1;
            }
        }
        __syncthreads();

        floatx4 acc00, acc01, acc10, acc11;
        {
            float4 c0 = *(const float4*)(bdL + mb + quad * 4);
            float4 c1 = *(const float4*)(bdL + mb + 16 + quad * 4);
            acc00 = acc01 = (floatx4){c0.x, c0.y, c0.z, c0.w};
            acc10 = acc11 = (floatx4){c1.x, c1.y, c1.z, c1.w};
        }

        // Conv GEMM: K=512 (s<8: tap0 = t-dil, s>=8: tap1 = t)
        #pragma unroll
        for (int s = 0; s < 16; ++s) {
            const int tbs = (s < 8 ? 0 : TAPSZ) + (s & 7) * 32;
            short8x a0 = *(const short8x*)(aw + s * 1024);
            short8x a1 = *(const short8x*)(aw + s * 1024 + 512);
            short8x g0 = *(const short8x*)&st[tbs + u0];
            short8x g1 = *(const short8x*)&st[tbs + u1];
            acc00 = __builtin_amdgcn_mfma_f32_16x16x32_bf16(a0, g0, acc00, 0, 0, 0);
            acc10 = __builtin_amdgcn_mfma_f32_16x16x32_bf16(a1, g0, acc10, 0, 0, 0);
            acc01 = __builtin_amdgcn_mfma_f32_16x16x32_bf16(a0, g1, acc01, 0, 0, 0);
            acc11 = __builtin_amdgcn_mfma_f32_16x16x32_bf16(a1, g1, acc11, 0, 0, 0);
        }
        __syncthreads();   // conv LDS reads done before gated overlays tap0

        // gate -> LDS gl[n][cin] (overlay tap0); capture t=8191 col fp32
        #pragma unroll
        for (int mt = 0; mt < 2; ++mt) {
            #pragma unroll
            for (int nt = 0; nt < 2; ++nt) {
                floatx4 a = mt == 0 ? (nt == 0 ? acc00 : acc01) : (nt == 0 ? acc10 : acc11);
                float gf[4];
                ull pk = 0;
                #pragma unroll
                for (int r = 0; r < 4; ++r) {
                    float d = a[r];
                    float sig = 1.f / (1.f + __expf(-d));
                    float th = 1.f - 2.f / (__expf(2.f * d) + 1.f);
                    gf[r] = th * sig;
                    pk |= ((ull)f2bf(gf[r])) << (16 * r);
                }
                const int n = nt * 16 + l16;
                const int m = mb + mt * 16 + quad * 4;
                *(ull*)&st[n * STR + m] = pk;
                if (tile == 0 && n == 31) {
                    float4 g4 = {gf[0], gf[1], gf[2], gf[3]};
                    *(float4*)&gstore[((size_t)i * BATCH + b) * RES + m] = g4;
                }
            }
        }
        __syncthreads();

        // Residual GEMM: h' = h + Wr @ gated, K=256
        floatx4 r00, r01, r10, r11;
        {
            float4 c0 = *(const float4*)(brL + mb + quad * 4);
            float4 c1 = *(const float4*)(brL + mb + 16 + quad * 4);
            r00 = r01 = (floatx4){c0.x, c0.y, c0.z, c0.w};
            r10 = r11 = (floatx4){c1.x, c1.y, c1.z, c1.w};
        }
        #pragma unroll
        for (int s = 0; s < 8; ++s) {
            short8x a0 = *(const short8x*)(rw + s * 1024);
            short8x a1 = *(const short8x*)(rw + s * 1024 + 512);
            short8x g0 = *(const short8x*)&st[s * 32 + u0];
            short8x g1 = *(const short8x*)&st[s * 32 + u1];
            r00 = __builtin_amdgcn_mfma_f32_16x16x32_bf16(a0, g0, r00, 0, 0, 0);
            r10 = __builtin_amdgcn_mfma_f32_16x16x32_bf16(a1, g0, r10, 0, 0, 0);
            r01 = __builtin_amdgcn_mfma_f32_16x16x32_bf16(a0, g1, r01, 0, 0, 0);
            r11 = __builtin_amdgcn_mfma_f32_16x16x32_bf16(a1, g1, r11, 0, 0, 0);
        }

        // Epilogue: coherent fp32 residual RMW + coherent bf16 copy; valid cols only
        #pragma unroll
        for (int nt = 0; nt < 2; ++nt) {
            const int t = tb + nt * 16 + l16;
            if (t < s_out) continue;
            const size_t base = (size_t)(t - T0) * RES;
            #pragma unroll
            for (int mt = 0; mt < 2; ++mt) {
                const int m = mb + mt * 16 + quad * 4;
                floatx4 ad = mt == 0 ? (nt == 0 ? r00 : r01) : (nt == 0 ? r10 : r11);
                ull* hfp = (ull*)(hfb + base + m);
                ull h0 = cload(hfp);
                ull h1 = cload(hfp + 1);
                float n0 = __uint_as_float((unsigned)h0) + ad[0];
                float n1 = __uint_as_float((unsigned)(h0 >> 32)) + ad[1];
                float n2 = __uint_as_float((unsigned)h1) + ad[2];
                float n3 = __uint_as_float((unsigned)(h1 >> 32)) + ad[3];
                cstore(hfp, ((ull)__float_as_uint(n1) << 32) | __float_as_uint(n0));
                cstore(hfp + 1, ((ull)__float_as_uint(n3) << 32) | __float_as_uint(n2));
                ull pk = (ull)f2bf(n0) | ((ull)f2bf(n1) << 16)
                       | ((ull)f2bf(n2) << 32) | ((ull)f2bf(n3) << 48);
                cstore((ull*)(hB + base + m), pk);
            }
        }

        // Publish: all waves drained -> set this unit's ready flag.
        asm volatile("s_waitcnt vmcnt(0)" ::: "memory");
        __syncthreads();
        if (tid == 0)
            __hip_atomic_store(flg + ((size_t)i * BATCH + b) * MAXTILES + tile, 1,
                               __ATOMIC_RELAXED, __HIP_MEMORY_SCOPE_AGENT);
        ntiles_prev = ntiles;
    }
}

// All 30 skip matvecs in parallel: block (l,b), thread o
__global__ __launch_bounds__(512) void skip_kernel(
    const ushort_t* __restrict__ WsT, const float* __restrict__ bs,
    const float* __restrict__ gstore, float* __restrict__ skip)
{
    const int l = blockIdx.x, b = blockIdx.y, o = threadIdx.x;
    const ushort_t* w = WsT + (size_t)l * 131072;
    const float* g = gstore + (size_t)(l * BATCH + b) * RES;
    float a = bs[l * SKIPC + o];
    #pragma unroll 4
    for (int cin = 0; cin < RES; ++cin)
        a = fmaf(bf2f(w[cin * SKIPC + o]), g[cin], a);
    atomicAdd(&skip[b * SKIPC + o], a);
}

// e1[b][o] = relu(W1 @ relu(skip[b]) + b1); grid (B, 16), block computes 32 outputs
__global__ __launch_bounds__(256) void end1_kernel(
    const float* __restrict__ skip, const float* __restrict__ W1,
    const float* __restrict__ b1, float* __restrict__ e1ws)
{
    __shared__ float s[SKIPC];
    __shared__ float part[256];
    const int b = blockIdx.x, og = blockIdx.y, tid = threadIdx.x;
    s[tid]       = fmaxf(skip[b * SKIPC + tid], 0.f);
    s[tid + 256] = fmaxf(skip[b * SKIPC + tid + 256], 0.f);
    __syncthreads();
    const int o_l = tid >> 3, kp = tid & 7;
    const int o = og * 32 + o_l;
    const float* w = W1 + (size_t)o * SKIPC + kp * 64;
    const float* sp = s + kp * 64;
    float a = 0.f;
    #pragma unroll 8
    for (int j = 0; j < 64; ++j) a = fmaf(w[j], sp[j], a);
    part[tid] = a;
    __syncthreads();
    if (tid < 32) {
        float r = b1[og * 32 + tid];
        #pragma unroll
        for (int k = 0; k < 8; ++k) r += part[tid * 8 + k];
        e1ws[b * SKIPC + og * 32 + tid] = fmaxf(r, 0.f);
    }
}

// out[b][cls] = W2 @ e1 + b2; grid (B, 8), block computes 32 outputs
__global__ __launch_bounds__(256) void end2_kernel(
    const float* __restrict__ e1ws, const float* __restrict__ W2,
    const float* __restrict__ b2, float* __restrict__ out)
{
    __shared__ float e[SKIPC];
    __shared__ float part[256];
    const int b = blockIdx.x, og = blockIdx.y, tid = threadIdx.x;
    e[tid]       = e1ws[b * SKIPC + tid];
    e[tid + 256] = e1ws[b * SKIPC + tid + 256];
    __syncthreads();
    const int o_l = tid >> 3, kp = tid & 7;
    const int cls = og * 32 + o_l;
    const float* w = W2 + (size_t)cls * SKIPC + kp * 64;
    const float* ep = e + kp * 64;
    float a = 0.f;
    #pragma unroll 8
    for (int j = 0; j < 64; ++j) a = fmaf(w[j], ep[j], a);
    part[tid] = a;
    __syncthreads();
    if (tid < 32) {
        float r = b2[og * 32 + tid];
        #pragma unroll
        for (int k = 0; k < 8; ++k) r += part[tid * 8 + k];
        out[b * NCLSC + og * 32 + tid] = r;
    }
}

extern "C" void kernel_launch(void* const* d_in, const int* in_sizes, int n_in,
                              void* d_out, int out_size, void* d_ws, size_t ws_size,
                              hipStream_t stream)
{
    const float* x   = (const float*)d_in[0];
    const float* Wst = (const float*)d_in[1];
    const float* bst = (const float*)d_in[2];
    const float* Wd  = (const float*)d_in[3];
    const float* bd  = (const float*)d_in[4];
    const float* Wr  = (const float*)d_in[5];
    const float* br  = (const float*)d_in[6];
    const float* Ws  = (const float*)d_in[7];
    const float* bs  = (const float*)d_in[8];
    const float* W1  = (const float*)d_in[9];
    const float* b1  = (const float*)d_in[10];
    const float* W2  = (const float*)d_in[11];
    const float* b2  = (const float*)d_in[12];
    float* out = (float*)d_out;

    char* w = (char*)d_ws;
    float* hf     = (float*)w;     w += (size_t)BATCH * TBUF * RES * 4;
    ushort_t* hb0 = (ushort_t*)w;  w += (size_t)BATCH * TBUF * RES * 2;
    ushort_t* hb1 = (ushort_t*)w;  w += (size_t)BATCH * TBUF * RES * 2;
    ushort_t* Asw = (ushort_t*)w;  w += (size_t)NLAYERS * RES * 512 * 2;
    ushort_t* Rsw = (ushort_t*)w;  w += (size_t)NLAYERS * RES * RES * 2;
    ushort_t* WsT = (ushort_t*)w;  w += (size_t)NLAYERS * RES * SKIPC * 2;
    float* gstore = (float*)w;     w += (size_t)NLAYERS * BATCH * RES * 4;
    float* skip   = (float*)w;     w += (size_t)BATCH * SKIPC * 4;
    float* e1ws   = (float*)w;     w += (size_t)BATCH * SKIPC * 4;
    int* flg      = (int*)w;       w += (size_t)NLAYERS * BATCH * MAXTILES * 4;

    prep_kernel<<<38400, 256, 0, stream>>>(Wd, Wr, Ws, Asw, Rsw, WsT);
    start_kernel<<<(BATCH * TBUF * RES) / 256, 256, 0, stream>>>(x, Wst, bst, hf, hb0);
    hipMemsetAsync(skip, 0, BATCH * SKIPC * 4, stream);
    hipMemsetAsync(flg, 0, (size_t)NLAYERS * BATCH * MAXTILES * 4, stream);

    fused_layers_kernel<<<GRIDP, 512, 0, stream>>>(
        hf, hb0, hb1, Asw, bd, Rsw, br, gstore, flg);

    skip_kernel<<<dim3(NLAYERS, BATCH), 512, 0, stream>>>(WsT, bs, gstore, skip);
    end1_kernel<<<dim3(BATCH, 16), 256, 0, stream>>>(skip, W1, b1, e1ws);
    end2_kernel<<<dim3(BATCH, 8), 256, 0, stream>>>(e1ws, W2, b2, out);
}

// Round 3
// 564.937 us; speedup vs baseline: 3.6653x; 1.2890x over previous
//
#include <hip/hip_runtime.h>

#define BATCH 4
#define T 8192
#define RES 256
#define SKIPC 512
#define NCLSC 256
#define NLAYERS 30
#define T0 5120
#define TBUF 3072
#define NT 32
#define STR 264               // LDS row stride in shorts (528 B): 2-way banks, 16B-aligned
#define TAPSZ (NT * STR)      // 8448 shorts per tap buffer
#define GRIDP 384             // tiles(96) x batch(4); 2 blocks/CU -> all co-resident
#define MAXTILES 96

typedef __attribute__((ext_vector_type(8))) short short8x;   // 8 bf16
typedef __attribute__((ext_vector_type(4))) float floatx4;   // MFMA C/D
typedef unsigned short ushort_t;
typedef unsigned long long ull;

__device__ __forceinline__ ushort_t f2bf(float f) {
    unsigned u = __float_as_uint(f);
    u += 0x7fffu + ((u >> 16) & 1u);
    return (ushort_t)(u >> 16);
}
__device__ __forceinline__ float bf2f(ushort_t h) {
    return __uint_as_float(((unsigned)h) << 16);
}

// Coherent (cross-XCD) 8B access: relaxed agent-scope atomics -> sc1 ops, no
// cache-maintenance. Used ONLY for the tap0 halo (hbC) and flags; everything
// else is plain-cached (same-block producer/consumer -> own L1/L2).
__device__ __forceinline__ ull cload(const ull* p) {
    return __hip_atomic_load(p, __ATOMIC_RELAXED, __HIP_MEMORY_SCOPE_AGENT);
}
__device__ __forceinline__ void cstore(ull* p, ull v) {
    __hip_atomic_store(p, v, __ATOMIC_RELAXED, __HIP_MEMORY_SCOPE_AGENT);
}

#define WAITF(P) while (__hip_atomic_load((P), __ATOMIC_RELAXED, __HIP_MEMORY_SCOPE_AGENT) == 0) \
                     __builtin_amdgcn_s_sleep(1)

// Weight prep: Aswz/Rswz in exact MFMA A-fragment load order (coalesced loads).
__global__ __launch_bounds__(256) void prep_kernel(
    const float* __restrict__ Wd, const float* __restrict__ Wr,
    const float* __restrict__ Ws,
    ushort_t* __restrict__ Aswz, ushort_t* __restrict__ Rswz,
    ushort_t* __restrict__ WsT)
{
    long id = (long)blockIdx.x * 256 + threadIdx.x;
    const long R0 = 30L * 131072, R1 = 30L * 65536, R2 = 30L * 131072;
    if (id < R0) {
        long l = id >> 17; int r = (int)(id & 131071);
        int j = r & 7, lane = (r >> 3) & 63, f = (r >> 9) & 1, s = (r >> 10) & 15, wv = r >> 14;
        int row = wv * 32 + f * 16 + (lane & 15);
        int k = s * 32 + (lane >> 4) * 8 + j;
        int cin = k & 255, kk = k >> 8;
        Aswz[id] = f2bf(Wd[((l * 256 + row) * 256 + cin) * 2 + kk]);
        return;
    }
    id -= R0;
    if (id < R1) {
        long l = id >> 16; int r = (int)(id & 65535);
        int j = r & 7, lane = (r >> 3) & 63, f = (r >> 9) & 1, s = (r >> 10) & 7, wv = r >> 13;
        int row = wv * 32 + f * 16 + (lane & 15);
        int k = s * 32 + (lane >> 4) * 8 + j;
        Rswz[id] = f2bf(Wr[(l * 256 + row) * 256 + k]);
        return;
    }
    id -= R1;
    if (id < R2) {
        int o = (int)(id & 511); long rest = id >> 9; int cin = (int)(rest & 255); long l = rest >> 8;
        WsT[id] = f2bf(Ws[(l * 512 + o) * 256 + cin]);
    }
}

// h0[b][t][c] for t in [5120, 8191], fp32 + bf16 copies.
__global__ __launch_bounds__(256) void start_kernel(
    const float* __restrict__ x, const float* __restrict__ Wst,
    const float* __restrict__ bst, float* __restrict__ hf, ushort_t* __restrict__ hb)
{
    int id = blockIdx.x * 256 + threadIdx.x;
    int c = id & 255;
    int ti = (id >> 8) % TBUF;
    int b  = (id >> 8) / TBUF;
    int t = T0 + ti;
    float v = Wst[2 * c] * x[b * T + t - 1] + Wst[2 * c + 1] * x[b * T + t] + bst[c];
    hf[id] = v;
    hb[id] = f2bf(v);
}

// All 30 layers dataflow-pipelined with a LAYER-STABLE tile<->block mapping
// (tile = B>>2): hf RMW + tap1 + hb ping-pong are same-block across layers ->
// plain cached (own L1/L2, no coherence needed). Only the tap0 halo crosses
// blocks: producer publishes min(dil_next,32) cols into a per-layer packed
// coherent buffer hbC (per-layer storage because producer/consumer skew is
// unbounded); consumer does ONE flag wait on its single remote producer tile.
__global__ __launch_bounds__(512, 4) void fused_layers_kernel(
    float* __restrict__ hf,
    ushort_t* __restrict__ hb0, ushort_t* __restrict__ hb1,
    const ushort_t* __restrict__ Asw,
    const float* __restrict__ bd,
    const ushort_t* __restrict__ Rsw,
    const float* __restrict__ br,
    float* __restrict__ gstore,
    ushort_t* __restrict__ hbC,
    int* __restrict__ flg)
{
    __shared__ __align__(16) ushort_t st[2 * TAPSZ];   // 33.8 KB; gated overlays tap0

    const int tid = threadIdx.x;
    const int wv = tid >> 6, lane = tid & 63;
    const int quad = lane >> 4, l16 = lane & 15;
    const int mb = wv * 32;
    const int u0 = l16 * STR + quad * 8;
    const int u1 = u0 + 16 * STR;
    const int B = blockIdx.x;
    const int tile = B >> 2;          // stable across layers (ntiles shrinks)
    const int b = B & 3;
    const int tb = 8192 - NT * (tile + 1);

    float* __restrict__ hfb = hf + (size_t)b * TBUF * RES;

    int rem = 3069;
    int ntiles_prev = 0;
    size_t cur_off = 0, prev_off = 0;

    for (int i = 0; i < NLAYERS; ++i) {
        const int dil = 1 << (i % 10);
        rem -= dil;                                    // rem[i+1]
        const int s_out = 8191 - rem;
        const int ntiles = (8192 - s_out + NT - 1) >> 5;
        if (tile >= ntiles) break;                     // shrinking: done forever

        const ushort_t* __restrict__ hA = ((i & 1) ? hb1 : hb0) + (size_t)b * TBUF * RES;
        ushort_t* __restrict__ hB = ((i & 1) ? hb0 : hb1) + (size_t)b * TBUF * RES;
        const ushort_t* __restrict__ aw =
            Asw + (size_t)i * (RES * 512) + (size_t)wv * 16384 + lane * 8;
        const ushort_t* __restrict__ rw =
            Rsw + (size_t)i * (RES * RES) + (size_t)wv * 8192 + lane * 8;
        const float* __restrict__ bdL = bd + i * RES;
        const float* __restrict__ brL = br + i * RES;

        // ---- remote tap0 halo bookkeeping ----
        const int dil_eff = (i == 0) ? 0 : (dil < 32 ? dil : 32);   // remote rows [0, dil_eff)
        const int rdelta = (dil < 32) ? 1 : (dil >> 5);
        const int r = tile + rdelta;                   // single remote producer tile
        const bool remote_valid = (i > 0) && (r < ntiles_prev);
        const ushort_t* hbCp = hbC;
        if (i > 0) {
            const int r_c = remote_valid ? r : (ntiles_prev - 1);
            hbCp = hbC + prev_off +
                   ((size_t)b * ntiles_prev + r_c) * (size_t)dil_eff * RES;
        }

        if (remote_valid && tid == 0)
            WAITF(flg + ((i - 1) * BATCH + b) * MAXTILES + r);
        __syncthreads();   // flag observed by all; also prev-layer LDS reads done

        // Stage tap0 (t-dil) and tap1 (t). Own data: plain cached (self-written
        // last layer, same CU). Remote halo rows (< dil_eff): coherent from hbC.
        #pragma unroll
        for (int tp = 0; tp < 2; ++tp) {
            #pragma unroll
            for (int p = 0; p < 2; ++p) {
                int c = p * 512 + tid;
                int row = c >> 5, offs = (c & 31) * 8;
                ull v0, v1;
                if (tp == 1) {
                    const ull* src = (const ull*)(hA + (size_t)(tb + row - T0) * RES + offs);
                    v0 = src[0]; v1 = src[1];
                } else if (row < dil_eff) {
                    const ull* src = (const ull*)(hbCp + (size_t)row * RES + offs);
                    v0 = cload(src); v1 = cload(src + 1);
                } else {
                    int tt = tb + row - dil - T0;
                    tt = tt < 0 ? 0 : tt;              // junk cols discarded in epilogue
                    const ull* src = (const ull*)(hA + (size_t)tt * RES + offs);
                    v0 = src[0]; v1 = src[1];
                }
                ull* dst = (ull*)&st[tp * TAPSZ + row * STR + offs];
                dst[0] = v0; dst[1] = v1;
            }
        }
        __syncthreads();

        floatx4 acc00, acc01, acc10, acc11;
        {
            float4 c0 = *(const float4*)(bdL + mb + quad * 4);
            float4 c1 = *(const float4*)(bdL + mb + 16 + quad * 4);
            acc00 = acc01 = (floatx4){c0.x, c0.y, c0.z, c0.w};
            acc10 = acc11 = (floatx4){c1.x, c1.y, c1.z, c1.w};
        }

        // Conv GEMM: K=512 (s<8: tap0 = t-dil, s>=8: tap1 = t)
        #pragma unroll
        for (int s = 0; s < 16; ++s) {
            const int tbs = (s < 8 ? 0 : TAPSZ) + (s & 7) * 32;
            short8x a0 = *(const short8x*)(aw + s * 1024);
            short8x a1 = *(const short8x*)(aw + s * 1024 + 512);
            short8x g0 = *(const short8x*)&st[tbs + u0];
            short8x g1 = *(const short8x*)&st[tbs + u1];
            acc00 = __builtin_amdgcn_mfma_f32_16x16x32_bf16(a0, g0, acc00, 0, 0, 0);
            acc10 = __builtin_amdgcn_mfma_f32_16x16x32_bf16(a1, g0, acc10, 0, 0, 0);
            acc01 = __builtin_amdgcn_mfma_f32_16x16x32_bf16(a0, g1, acc01, 0, 0, 0);
            acc11 = __builtin_amdgcn_mfma_f32_16x16x32_bf16(a1, g1, acc11, 0, 0, 0);
        }
        __syncthreads();   // conv LDS reads done before gated overlays tap0

        // gate -> LDS gl[n][cin] (overlay tap0); capture t=8191 col fp32
        #pragma unroll
        for (int mt = 0; mt < 2; ++mt) {
            #pragma unroll
            for (int nt = 0; nt < 2; ++nt) {
                floatx4 a = mt == 0 ? (nt == 0 ? acc00 : acc01) : (nt == 0 ? acc10 : acc11);
                float gf[4];
                ull pk = 0;
                #pragma unroll
                for (int rr = 0; rr < 4; ++rr) {
                    float d = a[rr];
                    float sig = 1.f / (1.f + __expf(-d));
                    float th = 1.f - 2.f / (__expf(2.f * d) + 1.f);
                    gf[rr] = th * sig;
                    pk |= ((ull)f2bf(gf[rr])) << (16 * rr);
                }
                const int n = nt * 16 + l16;
                const int m = mb + mt * 16 + quad * 4;
                *(ull*)&st[n * STR + m] = pk;
                if (tile == 0 && n == 31) {
                    float4 g4 = {gf[0], gf[1], gf[2], gf[3]};
                    *(float4*)&gstore[((size_t)i * BATCH + b) * RES + m] = g4;
                }
            }
        }
        __syncthreads();

        // Residual GEMM: h' = h + Wr @ gated, K=256
        floatx4 r00, r01, r10, r11;
        {
            float4 c0 = *(const float4*)(brL + mb + quad * 4);
            float4 c1 = *(const float4*)(brL + mb + 16 + quad * 4);
            r00 = r01 = (floatx4){c0.x, c0.y, c0.z, c0.w};
            r10 = r11 = (floatx4){c1.x, c1.y, c1.z, c1.w};
        }
        #pragma unroll
        for (int s = 0; s < 8; ++s) {
            short8x a0 = *(const short8x*)(rw + s * 1024);
            short8x a1 = *(const short8x*)(rw + s * 1024 + 512);
            short8x g0 = *(const short8x*)&st[s * 32 + u0];
            short8x g1 = *(const short8x*)&st[s * 32 + u1];
            r00 = __builtin_amdgcn_mfma_f32_16x16x32_bf16(a0, g0, r00, 0, 0, 0);
            r10 = __builtin_amdgcn_mfma_f32_16x16x32_bf16(a1, g0, r10, 0, 0, 0);
            r01 = __builtin_amdgcn_mfma_f32_16x16x32_bf16(a0, g1, r01, 0, 0, 0);
            r11 = __builtin_amdgcn_mfma_f32_16x16x32_bf16(a1, g1, r11, 0, 0, 0);
        }

        // ---- halo publish bookkeeping for THIS layer's output ----
        const int dnext = (i < NLAYERS - 1) ? (1 << ((i + 1) % 10)) : 0;
        const int Ci = (dnext < 32) ? dnext : 32;      // 0 when i==29
        const int dnx = (dnext >= 32) ? (dnext >> 5) : 1;
        const bool wrC = (Ci > 0) && (tile >= dnx);    // has a consumer
        ushort_t* hbCc = hbC + cur_off + ((size_t)b * ntiles + tile) * (size_t)Ci * RES;
        const int tminC = tb + 32 - Ci;

        // Epilogue: plain fp32 residual RMW + plain bf16 copy (self-read next
        // layer) + coherent halo copy to hbC for the remote consumer.
        #pragma unroll
        for (int nt = 0; nt < 2; ++nt) {
            const int t = tb + nt * 16 + l16;
            if (t < s_out) continue;
            const size_t base = (size_t)(t - T0) * RES;
            #pragma unroll
            for (int mt = 0; mt < 2; ++mt) {
                const int m = mb + mt * 16 + quad * 4;
                floatx4 ad = mt == 0 ? (nt == 0 ? r00 : r01) : (nt == 0 ? r10 : r11);
                float4 ho = *(const float4*)(hfb + base + m);
                float4 hn = {ho.x + ad[0], ho.y + ad[1], ho.z + ad[2], ho.w + ad[3]};
                *(float4*)(hfb + base + m) = hn;
                ull pk = (ull)f2bf(hn.x) | ((ull)f2bf(hn.y) << 16)
                       | ((ull)f2bf(hn.z) << 32) | ((ull)f2bf(hn.w) << 48);
                *(ull*)(hB + base + m) = pk;
                if (wrC && t >= tminC)
                    cstore((ull*)(hbCc + (size_t)(t - tminC) * RES + m), pk);
            }
        }

        // Publish: coherent halo stores drained -> set ready flag.
        asm volatile("s_waitcnt vmcnt(0)" ::: "memory");
        __syncthreads();
        if (tid == 0)
            __hip_atomic_store(flg + ((size_t)i * BATCH + b) * MAXTILES + tile, 1,
                               __ATOMIC_RELAXED, __HIP_MEMORY_SCOPE_AGENT);

        ntiles_prev = ntiles;
        prev_off = cur_off;
        cur_off += (size_t)4 * ntiles * Ci * RES;
    }
}

// All 30 skip matvecs in parallel: block (l,b), thread o
__global__ __launch_bounds__(512) void skip_kernel(
    const ushort_t* __restrict__ WsT, const float* __restrict__ bs,
    const float* __restrict__ gstore, float* __restrict__ skip)
{
    const int l = blockIdx.x, b = blockIdx.y, o = threadIdx.x;
    const ushort_t* w = WsT + (size_t)l * 131072;
    const float* g = gstore + (size_t)(l * BATCH + b) * RES;
    float a = bs[l * SKIPC + o];
    #pragma unroll 4
    for (int cin = 0; cin < RES; ++cin)
        a = fmaf(bf2f(w[cin * SKIPC + o]), g[cin], a);
    atomicAdd(&skip[b * SKIPC + o], a);
}

// e1[b][o] = relu(W1 @ relu(skip[b]) + b1); grid (B, 16), block computes 32 outputs
__global__ __launch_bounds__(256) void end1_kernel(
    const float* __restrict__ skip, const float* __restrict__ W1,
    const float* __restrict__ b1, float* __restrict__ e1ws)
{
    __shared__ float s[SKIPC];
    __shared__ float part[256];
    const int b = blockIdx.x, og = blockIdx.y, tid = threadIdx.x;
    s[tid]       = fmaxf(skip[b * SKIPC + tid], 0.f);
    s[tid + 256] = fmaxf(skip[b * SKIPC + tid + 256], 0.f);
    __syncthreads();
    const int o_l = tid >> 3, kp = tid & 7;
    const int o = og * 32 + o_l;
    const float* w = W1 + (size_t)o * SKIPC + kp * 64;
    const float* sp = s + kp * 64;
    float a = 0.f;
    #pragma unroll 8
    for (int j = 0; j < 64; ++j) a = fmaf(w[j], sp[j], a);
    part[tid] = a;
    __syncthreads();
    if (tid < 32) {
        float r = b1[og * 32 + tid];
        #pragma unroll
        for (int k = 0; k < 8; ++k) r += part[tid * 8 + k];
        e1ws[b * SKIPC + og * 32 + tid] = fmaxf(r, 0.f);
    }
}

// out[b][cls] = W2 @ e1 + b2; grid (B, 8), block computes 32 outputs
__global__ __launch_bounds__(256) void end2_kernel(
    const float* __restrict__ e1ws, const float* __restrict__ W2,
    const float* __restrict__ b2, float* __restrict__ out)
{
    __shared__ float e[SKIPC];
    __shared__ float part[256];
    const int b = blockIdx.x, og = blockIdx.y, tid = threadIdx.x;
    e[tid]       = e1ws[b * SKIPC + tid];
    e[tid + 256] = e1ws[b * SKIPC + tid + 256];
    __syncthreads();
    const int o_l = tid >> 3, kp = tid & 7;
    const int cls = og * 32 + o_l;
    const float* w = W2 + (size_t)cls * SKIPC + kp * 64;
    const float* ep = e + kp * 64;
    float a = 0.f;
    #pragma unroll 8
    for (int j = 0; j < 64; ++j) a = fmaf(w[j], ep[j], a);
    part[tid] = a;
    __syncthreads();
    if (tid < 32) {
        float r = b2[og * 32 + tid];
        #pragma unroll
        for (int k = 0; k < 8; ++k) r += part[tid * 8 + k];
        out[b * NCLSC + og * 32 + tid] = r;
    }
}

extern "C" void kernel_launch(void* const* d_in, const int* in_sizes, int n_in,
                              void* d_out, int out_size, void* d_ws, size_t ws_size,
                              hipStream_t stream)
{
    const float* x   = (const float*)d_in[0];
    const float* Wst = (const float*)d_in[1];
    const float* bst = (const float*)d_in[2];
    const float* Wd  = (const float*)d_in[3];
    const float* bd  = (const float*)d_in[4];
    const float* Wr  = (const float*)d_in[5];
    const float* br  = (const float*)d_in[6];
    const float* Ws  = (const float*)d_in[7];
    const float* bs  = (const float*)d_in[8];
    const float* W1  = (const float*)d_in[9];
    const float* b1  = (const float*)d_in[10];
    const float* W2  = (const float*)d_in[11];
    const float* b2  = (const float*)d_in[12];
    float* out = (float*)d_out;

    // hbC size: per layer, 4 * ntiles * C cols of 256 bf16 (C = min(dil_next,32))
    size_t hbC_shorts = 0;
    {
        int rem = 3069;
        for (int i = 0; i < NLAYERS; ++i) {
            int d = 1 << (i % 10);
            rem -= d;
            int ntl = (1 + rem + 31) >> 5;
            int dn = (i < NLAYERS - 1) ? (1 << ((i + 1) % 10)) : 0;
            int Ci = (dn < 32) ? dn : 32;
            hbC_shorts += (size_t)4 * ntl * Ci * RES;
        }
    }

    char* w = (char*)d_ws;
    float* hf     = (float*)w;     w += (size_t)BATCH * TBUF * RES * 4;
    ushort_t* hb0 = (ushort_t*)w;  w += (size_t)BATCH * TBUF * RES * 2;
    ushort_t* hb1 = (ushort_t*)w;  w += (size_t)BATCH * TBUF * RES * 2;
    ushort_t* Asw = (ushort_t*)w;  w += (size_t)NLAYERS * RES * 512 * 2;
    ushort_t* Rsw = (ushort_t*)w;  w += (size_t)NLAYERS * RES * RES * 2;
    ushort_t* WsT = (ushort_t*)w;  w += (size_t)NLAYERS * RES * SKIPC * 2;
    float* gstore = (float*)w;     w += (size_t)NLAYERS * BATCH * RES * 4;
    float* skip   = (float*)w;     w += (size_t)BATCH * SKIPC * 4;
    float* e1ws   = (float*)w;     w += (size_t)BATCH * SKIPC * 4;
    ushort_t* hbC = (ushort_t*)w;  w += hbC_shorts * 2;
    int* flg      = (int*)w;       w += (size_t)NLAYERS * BATCH * MAXTILES * 4;

    prep_kernel<<<38400, 256, 0, stream>>>(Wd, Wr, Ws, Asw, Rsw, WsT);
    start_kernel<<<(BATCH * TBUF * RES) / 256, 256, 0, stream>>>(x, Wst, bst, hf, hb0);
    hipMemsetAsync(skip, 0, BATCH * SKIPC * 4, stream);
    hipMemsetAsync(flg, 0, (size_t)NLAYERS * BATCH * MAXTILES * 4, stream);

    fused_layers_kernel<<<GRIDP, 512, 0, stream>>>(
        hf, hb0, hb1, Asw, bd, Rsw, br, gstore, hbC, flg);

    skip_kernel<<<dim3(NLAYERS, BATCH), 512, 0, stream>>>(WsT, bs, gstore, skip);
    end1_kernel<<<dim3(BATCH, 16), 256, 0, stream>>>(skip, W1, b1, e1ws);
    end2_kernel<<<dim3(BATCH, 8), 256, 0, stream>>>(e1ws, W2, b2, out);
}